// Round 3
// baseline (305.335 us; speedup 1.0000x reference)
//
#include <hip/hip_runtime.h>

// Problem dims (fixed by setup_inputs)
#define BATCH 4
#define HH 128
#define WW 128
#define CC 128
#define BIN 64
#define NPIX (BATCH * HH * WW)   // 65536

// ---------------------------------------------------------------------------
// Kernel 1: 1x1 conv == GEMM  Y[p][d] = sum_c X[p][c] * W[c][d]
// 256 threads, tile = 256 pixels x 128 d, K chunked by 32.
// 16x8 register tile: 6 ds_read_b128 per 128 FMA (DS pipe ~= VALU pipe).
// Ws rows store 8-float d-groups padded to 12 floats -> reads at tx*12 hit
// 8 distinct 4-bank groups (2-way only = free). Grid 512 = exactly 2/CU.
// ---------------------------------------------------------------------------
__global__ __launch_bounds__(256, 2)
void conv1x1_kernel(const float* __restrict__ Xm, const float* __restrict__ Xr,
                    const float* __restrict__ Wm, const float* __restrict__ Wr,
                    float* __restrict__ Ym, float* __restrict__ Yr) {
    const float* __restrict__ X = blockIdx.y ? Xr : Xm;
    const float* __restrict__ W = blockIdx.y ? Wr : Wm;
    float* __restrict__ Y       = blockIdx.y ? Yr : Ym;

    __shared__ float Xs[32 * 260];   // [c][px], px-pad 256->260
    __shared__ float Ws[32 * 192];   // [c][16 slots * 12]; slot s holds d=8s..8s+7

    const int t      = threadIdx.x;
    const int p_base = blockIdx.x * 256;
    const int tx = t & 15;           // d-slot
    const int ty = t >> 4;           // px-group
    const int p0 = ty * 16;

    float acc[16][8];
#pragma unroll
    for (int i = 0; i < 16; ++i)
#pragma unroll
        for (int j = 0; j < 8; ++j) acc[i][j] = 0.0f;

    for (int kc = 0; kc < CC; kc += 32) {
        __syncthreads();
        // stage X chunk transposed: thread t owns pixel p_base+t (32 c each)
        {
            const float4* xp = (const float4*)(X + (size_t)(p_base + t) * CC + kc);
#pragma unroll
            for (int g = 0; g < 8; ++g) {
                float4 v = xp[g];
                Xs[(g * 4 + 0) * 260 + t] = v.x;
                Xs[(g * 4 + 1) * 260 + t] = v.y;
                Xs[(g * 4 + 2) * 260 + t] = v.z;
                Xs[(g * 4 + 3) * 260 + t] = v.w;
            }
        }
        // stage W chunk into padded layout
#pragma unroll
        for (int i = 0; i < 4; ++i) {
            const int s = t + i * 256;
            const int c = s >> 5;
            const int g = s & 31;          // logical float4 index (d = 4g)
            float4 v = *(const float4*)(W + (size_t)(kc + c) * CC + g * 4);
            *(float4*)&Ws[c * 192 + (g >> 1) * 12 + (g & 1) * 4] = v;
        }
        __syncthreads();

#pragma unroll 2
        for (int c = 0; c < 32; ++c) {
            const float* xrow = &Xs[c * 260 + p0];
            float4 xa = *(const float4*)(xrow);
            float4 xb = *(const float4*)(xrow + 4);
            float4 xc2 = *(const float4*)(xrow + 8);
            float4 xd = *(const float4*)(xrow + 12);
            const float* wrow = &Ws[c * 192 + tx * 12];
            float4 w0 = *(const float4*)(wrow);
            float4 w1 = *(const float4*)(wrow + 4);
            float xs[16] = {xa.x, xa.y, xa.z, xa.w, xb.x, xb.y, xb.z, xb.w,
                            xc2.x, xc2.y, xc2.z, xc2.w, xd.x, xd.y, xd.z, xd.w};
            float ws[8]  = {w0.x, w0.y, w0.z, w0.w, w1.x, w1.y, w1.z, w1.w};
#pragma unroll
            for (int i = 0; i < 16; ++i)
#pragma unroll
                for (int j = 0; j < 8; ++j) acc[i][j] += xs[i] * ws[j];
        }
    }

#pragma unroll
    for (int i = 0; i < 16; ++i) {
        float* yrow = &Y[(size_t)(p_base + p0 + i) * CC + tx * 8];
        float4 o0 = {acc[i][0], acc[i][1], acc[i][2], acc[i][3]};
        float4 o1 = {acc[i][4], acc[i][5], acc[i][6], acc[i][7]};
        *(float4*)(yrow)     = o0;
        *(float4*)(yrow + 4) = o1;
    }
}

// ---------------------------------------------------------------------------
// Kernel 2: local 5x5 attention, LDS-tiled.
// One block per 16x16 pixel tile (256 threads, 1 thread/pixel). The 20x20
// halo of k (4 chunks x 32ch) then v (2 chunks x 32ch) is staged into one
// 51.2 KB LDS buffer. XOR swizzle on the float4-group index ((g ^ (px&7)))
// makes staging writes AND 25-neighbor reads bank-conflict-free.
// OOB halo is staged as ZERO -> no validity branches in compute loops, and
// semantics match the reference's zero-padded extract_patches exactly
// (OOB logit = 0 participates in softmax; OOB value = 0).
// ---------------------------------------------------------------------------
__global__ __launch_bounds__(256, 2)
void attn_kernel(const float* __restrict__ qm,   // conv_main [NPIX][128]
                 const float* __restrict__ kr,   // conv_ref  [NPIX][128]
                 const float* __restrict__ vv,   // ref_value [NPIX][64]
                 float* __restrict__ out) {      // [NPIX][64]
    __shared__ float4 KS[400 * 8];   // 20x20 halo x 32 ch (as 8 float4 groups)

    const int t  = threadIdx.x;
    const int bi = blockIdx.x >> 6;          // batch
    const int tyv = (blockIdx.x >> 3) & 7;   // tile row
    const int txv = blockIdx.x & 7;          // tile col
    const int h0 = tyv * 16;
    const int w0 = txv * 16;

    const int r = t >> 4;                    // local pixel row
    const int c = t & 15;                    // local pixel col
    const int pix = ((bi * HH + h0 + r) * WW + (w0 + c));

    float lg[25];
#pragma unroll
    for (int i = 0; i < 25; ++i) lg[i] = 0.0f;

    // ---- logits over 4 channel chunks ----
    for (int ch = 0; ch < 4; ++ch) {
        __syncthreads();
        // stage k halo chunk (zero OOB)
        for (int s = t; s < 3200; s += 256) {
            const int px = s >> 3;
            const int g  = s & 7;
            const int py = px / 20;
            const int pxx = px - py * 20;
            const int hh = h0 + py - 2;
            const int ww = w0 + pxx - 2;
            float4 val = make_float4(0.f, 0.f, 0.f, 0.f);
            if (((unsigned)hh < (unsigned)HH) && ((unsigned)ww < (unsigned)WW)) {
                const int gpix = (bi * HH + hh) * WW + ww;
                val = *(const float4*)(kr + (size_t)gpix * CC + ch * 32 + g * 4);
            }
            KS[px * 8 + (g ^ (px & 7))] = val;
        }
        __syncthreads();

        float4 q[8];
        {
            const float4* qp = (const float4*)(qm + (size_t)pix * CC + ch * 32);
#pragma unroll
            for (int g = 0; g < 8; ++g) q[g] = qp[g];
        }

#pragma unroll
        for (int dy = 0; dy < 5; ++dy) {
#pragma unroll
            for (int dx = 0; dx < 5; ++dx) {
                const int hp = (r + dy) * 20 + (c + dx);
                const int sw = hp & 7;
                const int base = hp * 8;
                float part = 0.0f;
#pragma unroll
                for (int g = 0; g < 8; ++g) {
                    float4 kv = KS[base + (g ^ sw)];
                    part += q[g].x * kv.x + q[g].y * kv.y +
                            q[g].z * kv.z + q[g].w * kv.w;
                }
                lg[dy * 5 + dx] += part;
            }
        }
    }

    // ---- softmax over 25 (in registers) ----
    float m = lg[0];
#pragma unroll
    for (int i = 1; i < 25; ++i) m = fmaxf(m, lg[i]);
    float ssum = 0.0f;
#pragma unroll
    for (int i = 0; i < 25; ++i) {
        lg[i] = __expf(lg[i] - m);
        ssum += lg[i];
    }
    const float inv = 1.0f / ssum;
#pragma unroll
    for (int i = 0; i < 25; ++i) lg[i] *= inv;

    // ---- value mix over 2 BIN chunks (reuse KS buffer) ----
    for (int vc = 0; vc < 2; ++vc) {
        __syncthreads();
        for (int s = t; s < 3200; s += 256) {
            const int px = s >> 3;
            const int g  = s & 7;
            const int py = px / 20;
            const int pxx = px - py * 20;
            const int hh = h0 + py - 2;
            const int ww = w0 + pxx - 2;
            float4 val = make_float4(0.f, 0.f, 0.f, 0.f);
            if (((unsigned)hh < (unsigned)HH) && ((unsigned)ww < (unsigned)WW)) {
                const int gpix = (bi * HH + hh) * WW + ww;
                val = *(const float4*)(vv + (size_t)gpix * BIN + vc * 32 + g * 4);
            }
            KS[px * 8 + (g ^ (px & 7))] = val;
        }
        __syncthreads();

        float4 va[8];
#pragma unroll
        for (int g = 0; g < 8; ++g) va[g] = make_float4(0.f, 0.f, 0.f, 0.f);

#pragma unroll
        for (int dy = 0; dy < 5; ++dy) {
#pragma unroll
            for (int dx = 0; dx < 5; ++dx) {
                const int hp = (r + dy) * 20 + (c + dx);
                const int sw = hp & 7;
                const int base = hp * 8;
                const float wgt = lg[dy * 5 + dx];
#pragma unroll
                for (int g = 0; g < 8; ++g) {
                    float4 v = KS[base + (g ^ sw)];
                    va[g].x += wgt * v.x;
                    va[g].y += wgt * v.y;
                    va[g].z += wgt * v.z;
                    va[g].w += wgt * v.w;
                }
            }
        }

        float4* op = (float4*)(out + (size_t)pix * BIN + vc * 32);
#pragma unroll
        for (int g = 0; g < 8; ++g) op[g] = va[g];
    }
}

extern "C" void kernel_launch(void* const* d_in, const int* in_sizes, int n_in,
                              void* d_out, int out_size, void* d_ws, size_t ws_size,
                              hipStream_t stream) {
    const float* main_in   = (const float*)d_in[0];
    const float* ref_in    = (const float*)d_in[1];
    const float* ref_value = (const float*)d_in[2];
    const float* W_main    = (const float*)d_in[3];
    const float* W_ref     = (const float*)d_in[4];
    float* out = (float*)d_out;

    float* conv_main = (float*)d_ws;                         // 32 MB
    float* conv_ref  = conv_main + (size_t)NPIX * CC;        // 32 MB

    dim3 gconv(NPIX / 256, 2);   // 512 blocks = exactly 2/CU
    conv1x1_kernel<<<gconv, 256, 0, stream>>>(main_in, ref_in, W_main, W_ref,
                                              conv_main, conv_ref);

    // 256 blocks: one 16x16 tile each (4 batches x 8x8 tiles)
    attn_kernel<<<256, 256, 0, stream>>>(conv_main, conv_ref, ref_value, out);
}

// Round 4
// 193.860 us; speedup vs baseline: 1.5750x; 1.5750x over previous
//
#include <hip/hip_runtime.h>

// Problem dims (fixed by setup_inputs)
#define BATCH 4
#define HH 128
#define WW 128
#define CC 128
#define BIN 64
#define NPIX (BATCH * HH * WW)   // 65536

typedef short bf16x8 __attribute__((ext_vector_type(8)));
typedef float f32x4 __attribute__((ext_vector_type(4)));

// round-to-nearest-even bf16 bits of f
__device__ __forceinline__ unsigned bf_hi(float f) {
    unsigned u = __float_as_uint(f);
    return (u + 0x7fffu + ((u >> 16) & 1u)) >> 16;
}
// A-operand split: per c, k' slots [4c..4c+3] = [xh, xh, xl, xl]
__device__ __forceinline__ uint2 split_aa(float f) {
    unsigned hb = bf_hi(f);
    float lo = f - __uint_as_float(hb << 16);
    unsigned lb = bf_hi(lo);
    return make_uint2(hb | (hb << 16), lb | (lb << 16));
}
// B-operand split: per c, k' slots = [wh, wl, wh, wl] -> same uint twice
__device__ __forceinline__ unsigned split_b(float f) {
    unsigned hb = bf_hi(f);
    float lo = f - __uint_as_float(hb << 16);
    unsigned lb = bf_hi(lo);
    return hb | (lb << 16);
}

// ---------------------------------------------------------------------------
// Kernel 1: 1x1 conv == GEMM via split-bf16 MFMA.
// Y[p][d] = sum_c X[p][c]*W[c][d], fp32 reproduced as
// (xh+xl)*(wh+wl) with K'=512 (4 bf16 slots per c). 128px x 128d tile,
// K' chunked by 64 (16 c). 4 waves in 2x2, each 64x64 via 4x4 16x16x32 frags.
// Rows padded to 72 bf16 (144 B) -> b128 frag reads conflict-free at floor.
// ---------------------------------------------------------------------------
#define AROW 72   // shorts per LDS row (64 k' + 8 pad)

__global__ __launch_bounds__(256, 3)
void conv_mfma_kernel(const float* __restrict__ Xm, const float* __restrict__ Xr,
                      const float* __restrict__ Wm, const float* __restrict__ Wr,
                      float* __restrict__ Ym, float* __restrict__ Yr) {
    const float* __restrict__ X = blockIdx.y ? Xr : Xm;
    const float* __restrict__ W = blockIdx.y ? Wr : Wm;
    float* __restrict__ Y       = blockIdx.y ? Yr : Ym;

    __shared__ unsigned short AT[128 * AROW];   // [px][k'] 18 KB
    __shared__ unsigned short BT[128 * AROW];   // [d][k']  18 KB

    const int t  = threadIdx.x;
    const int wv = t >> 6;
    const int l  = t & 63;
    const int wm = (wv >> 1) * 64;   // wave's px-quadrant
    const int wn = (wv & 1) * 64;    // wave's d-quadrant
    const int lr = l & 15;
    const int lq = l >> 4;
    const int p_base = blockIdx.x * 128;

    const int px = t >> 1, ahalf = t & 1;   // A staging: 2 thr/px, 8 c each
    const int d  = t & 127, bq = t >> 7;    // B staging: 2 thr/d, 8 c each

    f32x4 acc[4][4] = {};

    for (int kc = 0; kc < CC; kc += 16) {   // 16 c per chunk = 64 k'
        __syncthreads();
        // ---- stage A (fp32 -> [h,h,l,l] bf16) ----
        {
            const float* xp = X + (size_t)(p_base + px) * CC + kc + ahalf * 8;
            unsigned short* arow = &AT[px * AROW + ahalf * 32];
#pragma unroll
            for (int i = 0; i < 2; ++i) {
                float4 v = *(const float4*)(xp + 4 * i);
                uint2 a0 = split_aa(v.x), a1 = split_aa(v.y),
                      a2 = split_aa(v.z), a3 = split_aa(v.w);
                *(uint4*)(arow + 16 * i)     = make_uint4(a0.x, a0.y, a1.x, a1.y);
                *(uint4*)(arow + 16 * i + 8) = make_uint4(a2.x, a2.y, a3.x, a3.y);
            }
        }
        // ---- stage B (fp32 -> [h,l,h,l] bf16, transposed to [d][k']) ----
        {
#pragma unroll
            for (int j = 0; j < 2; ++j) {
                const int cg = bq * 2 + j;                   // 4-c group 0..3
                const float* wp = W + (size_t)(kc + cg * 4) * CC + d;
                unsigned b0 = split_b(wp[0]);
                unsigned b1 = split_b(wp[CC]);
                unsigned b2 = split_b(wp[2 * CC]);
                unsigned b3 = split_b(wp[3 * CC]);
                unsigned short* brow = &BT[d * AROW + cg * 16];
                *(uint4*)(brow)     = make_uint4(b0, b0, b1, b1);
                *(uint4*)(brow + 8) = make_uint4(b2, b2, b3, b3);
            }
        }
        __syncthreads();
        // ---- MFMA: 2 k-steps of 32 ----
#pragma unroll
        for (int ks = 0; ks < 2; ++ks) {
            bf16x8 af[4], bfr[4];
#pragma unroll
            for (int mi = 0; mi < 4; ++mi)
                af[mi] = *(const bf16x8*)&AT[(wm + mi * 16 + lr) * AROW + ks * 32 + lq * 8];
#pragma unroll
            for (int ni = 0; ni < 4; ++ni)
                bfr[ni] = *(const bf16x8*)&BT[(wn + ni * 16 + lr) * AROW + ks * 32 + lq * 8];
#pragma unroll
            for (int mi = 0; mi < 4; ++mi)
#pragma unroll
                for (int ni = 0; ni < 4; ++ni)
                    acc[mi][ni] = __builtin_amdgcn_mfma_f32_16x16x32_bf16(
                        af[mi], bfr[ni], acc[mi][ni], 0, 0, 0);
        }
    }

    // epilogue: C/D layout col=lane&15, row=(lane>>4)*4+reg
#pragma unroll
    for (int mi = 0; mi < 4; ++mi)
#pragma unroll
        for (int ni = 0; ni < 4; ++ni)
#pragma unroll
            for (int reg = 0; reg < 4; ++reg) {
                const int row = p_base + wm + mi * 16 + lq * 4 + reg;
                Y[(size_t)row * CC + wn + ni * 16 + lr] = acc[mi][ni][reg];
            }
}

// ---------------------------------------------------------------------------
// Kernel 2: local 5x5 attention, LDS-tiled with async prefetch.
// 8x16 px tile (grid 512 = 2 blocks/CU), 128 thr (1/px). Halo = 12x20.
// 6 phases (4 k-chunks + 2 v-chunks of 32 ch) double-buffered: next chunk is
// DMA'd via global_load_lds BEFORE computing current -> barrier drain overlaps
// compute. g-major layout KS[g][halo_px]: reads are 16B-stride conflict-free,
// and DMA dest is exactly base + lane*16 (slot s = i*64+lane).
// OOB: staged addresses are CLAMPED (garbage never used); logits of invalid
// neighbors forced to 0 (== reference's zero-padded conv_ref dot) and their
// softmax weights forced to 0 (== zero-padded values).
// ---------------------------------------------------------------------------
#define TH 8
#define TW 16
#define HALO_W 20
#define HPX 240        // 12*20 halo pixels
#define NSLOT 1920     // HPX * 8 float4 groups

__global__ __launch_bounds__(128, 1)
void attn_tile_kernel(const float* __restrict__ qm, const float* __restrict__ kr,
                      const float* __restrict__ vv, float* __restrict__ out) {
    __shared__ float4 KS[2][NSLOT];   // 60 KB

    const int t   = threadIdx.x;
    const int wid = t >> 6;
    const int ln  = t & 63;

    const int bi = blockIdx.x >> 7;           // batch
    const int ty = (blockIdx.x >> 3) & 15;    // 16 tile-rows of 8
    const int tx = blockIdx.x & 7;            // 8 tile-cols of 16
    const int h0 = ty * TH, w0 = tx * TW;
    const int r = t >> 4, c = t & 15;
    const int h = h0 + r, w = w0 + c;
    const int gbase = bi * HH * WW;
    const int pix = gbase + h * WW + w;

    // 25-bit validity mask for this pixel's window
    unsigned vm = 0;
#pragma unroll
    for (int dy = 0; dy < 5; ++dy)
#pragma unroll
        for (int dx = 0; dx < 5; ++dx) {
            const int hh = h + dy - 2, ww = w + dx - 2;
            if ((unsigned)hh < (unsigned)HH && (unsigned)ww < (unsigned)WW)
                vm |= 1u << (dy * 5 + dx);
        }

    auto stage = [&](int p, int buf) {
        const float* src = (p < 4) ? kr : vv;
        const int ld = (p < 4) ? CC : BIN;
        const int ch = (p < 4) ? p * 32 : (p - 4) * 32;
        for (int i = wid; i < NSLOT / 64; i += 2) {
            const int s   = i * 64 + ln;
            const int g   = s / HPX;            // float4 group 0..7
            const int px  = s - g * HPX;        // halo pixel 0..239
            const int py  = px / HALO_W;
            const int pxx = px - py * HALO_W;
            int hh = h0 + py - 2;  hh = hh < 0 ? 0 : (hh > HH - 1 ? HH - 1 : hh);
            int ww = w0 + pxx - 2; ww = ww < 0 ? 0 : (ww > WW - 1 ? WW - 1 : ww);
            const float* gp = src + (size_t)(gbase + hh * WW + ww) * ld + ch + g * 4;
            __builtin_amdgcn_global_load_lds(
                (const __attribute__((address_space(1))) void*)gp,
                (__attribute__((address_space(3))) void*)&KS[buf][i * 64],
                16, 0, 0);
        }
    };

    float lg[25];
#pragma unroll
    for (int i = 0; i < 25; ++i) lg[i] = 0.0f;

    stage(0, 0);
    __syncthreads();

    for (int p = 0; p < 6; ++p) {
        if (p < 5) stage(p + 1, (p + 1) & 1);   // prefetch into other buffer
        const float4* B = KS[p & 1];
        if (p < 4) {
            // ---- logits chunk: 32 channels ----
            float4 q[8];
            const float4* qp = (const float4*)(qm + (size_t)pix * CC + p * 32);
#pragma unroll
            for (int g = 0; g < 8; ++g) q[g] = qp[g];
#pragma unroll
            for (int dy = 0; dy < 5; ++dy)
#pragma unroll
                for (int dx = 0; dx < 5; ++dx) {
                    const int hp = (r + dy) * HALO_W + (c + dx);
                    float part = 0.0f;
#pragma unroll
                    for (int g = 0; g < 8; ++g) {
                        float4 kv = B[g * HPX + hp];
                        part += q[g].x * kv.x + q[g].y * kv.y +
                                q[g].z * kv.z + q[g].w * kv.w;
                    }
                    lg[dy * 5 + dx] += part;
                }
        } else {
            if (p == 4) {
                // mask OOB logits to 0 (exact zero-pad semantics), softmax,
                // then zero the weights of OOB neighbors
#pragma unroll
                for (int kk = 0; kk < 25; ++kk)
                    if (!((vm >> kk) & 1)) lg[kk] = 0.0f;
                float mx = lg[0];
#pragma unroll
                for (int kk = 1; kk < 25; ++kk) mx = fmaxf(mx, lg[kk]);
                float sum = 0.0f;
#pragma unroll
                for (int kk = 0; kk < 25; ++kk) {
                    lg[kk] = __expf(lg[kk] - mx);
                    sum += lg[kk];
                }
                const float inv = 1.0f / sum;
#pragma unroll
                for (int kk = 0; kk < 25; ++kk)
                    lg[kk] = ((vm >> kk) & 1) ? lg[kk] * inv : 0.0f;
            }
            // ---- value-mix chunk: 32 bins ----
            float4 va[8];
#pragma unroll
            for (int g = 0; g < 8; ++g) va[g] = make_float4(0.f, 0.f, 0.f, 0.f);
#pragma unroll
            for (int dy = 0; dy < 5; ++dy)
#pragma unroll
                for (int dx = 0; dx < 5; ++dx) {
                    const float wgt = lg[dy * 5 + dx];
                    const int hp = (r + dy) * HALO_W + (c + dx);
#pragma unroll
                    for (int g = 0; g < 8; ++g) {
                        float4 v = B[g * HPX + hp];
                        va[g].x += wgt * v.x; va[g].y += wgt * v.y;
                        va[g].z += wgt * v.z; va[g].w += wgt * v.w;
                    }
                }
            float4* op = (float4*)(out + (size_t)pix * BIN + (p - 4) * 32);
#pragma unroll
            for (int g = 0; g < 8; ++g) op[g] = va[g];
        }
        __syncthreads();
    }
}

extern "C" void kernel_launch(void* const* d_in, const int* in_sizes, int n_in,
                              void* d_out, int out_size, void* d_ws, size_t ws_size,
                              hipStream_t stream) {
    const float* main_in   = (const float*)d_in[0];
    const float* ref_in    = (const float*)d_in[1];
    const float* ref_value = (const float*)d_in[2];
    const float* W_main    = (const float*)d_in[3];
    const float* W_ref     = (const float*)d_in[4];
    float* out = (float*)d_out;

    float* conv_main = (float*)d_ws;                         // 32 MB
    float* conv_ref  = conv_main + (size_t)NPIX * CC;        // 32 MB

    dim3 gconv(NPIX / 128, 2);   // 1024 blocks
    conv_mfma_kernel<<<gconv, 256, 0, stream>>>(main_in, ref_in, W_main, W_ref,
                                                conv_main, conv_ref);

    // 512 blocks = 2/CU: one 8x16 tile each (4 batches x 16x8 tiles)
    attn_tile_kernel<<<512, 128, 0, stream>>>(conv_main, conv_ref, ref_value, out);
}